// Round 1
// baseline (1266.490 us; speedup 1.0000x reference)
//
#include <hip/hip_runtime.h>

#define K_DIM 4096
#define N_DIM 11008
#define NPACK (N_DIM / 8)   // 1376 packed int32 per k-row

// fallback (128^2) geometry
#define BM 128
#define BN 128
#define BK 32

// main gemm (256^2) geometry
#define BM2 256
#define BN2 256
#define BK2 32
#define NT2 (K_DIM / BK2)   // 128 K-tiles

typedef __bf16 bf16x8 __attribute__((ext_vector_type(8)));
typedef float f32x4 __attribute__((ext_vector_type(4)));
typedef unsigned short u16x8 __attribute__((ext_vector_type(8)));

// fp32 -> bf16 bits, round-to-nearest-even (finite inputs only)
__device__ __forceinline__ unsigned short f2bf(float f) {
    unsigned u = __builtin_bit_cast(unsigned, f);
    return (unsigned short)((u + 0x7FFFu + ((u >> 16) & 1u)) >> 16);
}
__device__ __forceinline__ unsigned pack2bf(float a, float b) {
    return (unsigned)f2bf(a) | ((unsigned)f2bf(b) << 16);
}

// async global->LDS, 16B per lane; LDS dest = wave-uniform base + lane*16
#define GLD16(gp, lp) __builtin_amdgcn_global_load_lds(                       \
    (const __attribute__((address_space(1))) void*)(gp),                      \
    (__attribute__((address_space(3))) void*)(lp), 16, 0, 0)

#define MEMFENCE() asm volatile("" ::: "memory")

// ---------------------------------------------------------------------------
// Prepass 1: x fp32 [M][K] -> bf16 [M][K]. 8 elements/thread.
__global__ __launch_bounds__(256)
void convert_x(const float* __restrict__ x, unsigned short* __restrict__ xb)
{
    const size_t i = ((size_t)blockIdx.x * 256 + threadIdx.x) * 8;
    const float4 v0 = *reinterpret_cast<const float4*>(x + i);
    const float4 v1 = *reinterpret_cast<const float4*>(x + i + 4);
    u16x8 o;
    o[0] = f2bf(v0.x); o[1] = f2bf(v0.y); o[2] = f2bf(v0.z); o[3] = f2bf(v0.w);
    o[4] = f2bf(v1.x); o[5] = f2bf(v1.y); o[6] = f2bf(v1.z); o[7] = f2bf(v1.w);
    *reinterpret_cast<u16x8*>(xb + i) = o;
}

// ---------------------------------------------------------------------------
// Prepass 2: dequant int4 W[k][n] -> bf16 Wt[n][k] (transposed), 64x64 tiles.
__global__ __launch_bounds__(256)
void dequant_w(const int* __restrict__ qw, const float* __restrict__ scales,
               const int* __restrict__ qz, unsigned short* __restrict__ wt)
{
    __shared__ unsigned short T[64][76];   // [k][n], +12 pad halves col-read conflicts
    const int n0 = blockIdx.x * 64;
    const int k0 = blockIdx.y * 64;
    const int tid = threadIdx.x;

    #pragma unroll
    for (int h = 0; h < 2; ++h) {
        const int ii = tid + h * 256;            // [0,512): 64 k-rows x 8 packed ints
        const int kl = ii >> 3;
        const int nq = ii & 7;
        const unsigned q  = (unsigned)qw[(size_t)(k0 + kl) * NPACK + (n0 >> 3) + nq];
        const unsigned zq = (unsigned)qz[(n0 >> 3) + nq];
        const float4 s0 = *reinterpret_cast<const float4*>(scales + n0 + nq * 8);
        const float4 s1 = *reinterpret_cast<const float4*>(scales + n0 + nq * 8 + 4);
        const float s[8] = {s0.x, s0.y, s0.z, s0.w, s1.x, s1.y, s1.z, s1.w};
        u16x8 o;
        #pragma unroll
        for (int j = 0; j < 8; ++j) {
            const int   nib = (int)((q  >> (4 * j)) & 0xFu);
            const int   zp  = (int)((zq >> (4 * j)) & 0xFu);
            o[j] = f2bf((float)(nib - zp) * s[j]);
        }
        *reinterpret_cast<u16x8*>(&T[kl][nq * 8]) = o;
    }
    __syncthreads();
    #pragma unroll
    for (int h = 0; h < 2; ++h) {
        const int oo = tid + h * 256;            // [0,512): 64 n-rows x 8 k-chunks
        const int nl = oo >> 3;
        const int c  = oo & 7;
        u16x8 o;
        #pragma unroll
        for (int r = 0; r < 8; ++r) o[r] = T[c * 8 + r][nl];
        *reinterpret_cast<u16x8*>(wt + (size_t)(n0 + nl) * K_DIM + k0 + c * 8) = o;
    }
}

// ---------------------------------------------------------------------------
// Main GEMM: A bf16 [M][K], B bf16 [N][K] (both k-contiguous), out fp32 [M][N].
// 256x256 tile, 512 threads / 8 waves (2M x 4N), BK=32, triple-buffered LDS,
// depth-2 prefetch with counted vmcnt(4) across tile barriers (T3+T4),
// setprio around MFMA clusters (T5), XCD-chunked raster (T1).
__global__ __launch_bounds__(512, 2)
void gemm256(const unsigned short* __restrict__ A, const unsigned short* __restrict__ B,
             const float* __restrict__ bias, float* __restrict__ out)
{
    __shared__ unsigned short As[3][BM2 * BK2];   // 3 x 16 KB
    __shared__ unsigned short Bs[3][BN2 * BK2];   // 3 x 16 KB  (96 KB total)

    const int tid  = threadIdx.x;
    const int lane = tid & 63;
    const int wv   = tid >> 6;

    // block raster: 1376 = 8 XCD chunks of 172 = (4 M-rows x 43 N-cols),
    // column-major within chunk -> B panel L2-hit x4, A set cycles per XCD.
    int bx, by;
    if (gridDim.x == 43 && gridDim.y == 32) {
        const int bid = (int)(blockIdx.y * 43 + blockIdx.x);
        const int g   = bid & 7;          // XCD
        const int loc = bid >> 3;         // [0,172)
        by = g * 4 + (loc & 3);
        bx = loc >> 2;
    } else {
        bx = blockIdx.x; by = blockIdx.y;
    }
    const int bm0 = by * BM2;
    const int bn0 = bx * BN2;

    // staging geometry: thread t covers row (t>>2) of a 128-row half, bf16 col (t&3)*8.
    // LDS image is linear: chunk index == t, dest = wave-uniform base + lane*16B.
    const int srow = tid >> 2;
    const int sc   = (tid & 3) * 8;
    const unsigned short* gA0 = A + (size_t)(bm0 + srow) * K_DIM + sc;
    const unsigned short* gA1 = gA0 + (size_t)128 * K_DIM;
    const unsigned short* gB0 = B + (size_t)(bn0 + srow) * K_DIM + sc;
    const unsigned short* gB1 = gB0 + (size_t)128 * K_DIM;
    const int wvo = wv * 512;             // wave chunk offset within a 128-row half (ushorts)

    // fragment geometry (verified 16x16x32 layout from prior kernel)
    const int quad = lane >> 4;
    const int l16  = lane & 15;
    const int wmi  = wv >> 2;             // M half   (128 rows)
    const int wni  = wv & 3;              // N quarter (64 cols)
    const int aoff = (wmi * 128 + l16) * BK2 + quad * 8;
    const int boff = (wni * 64  + l16) * BK2 + quad * 8;

    f32x4 acc[8][4] = {};

    // prologue: stage tiles 0 and 1; keep tile1's 4 loads in flight
    GLD16(gA0,      &As[0][wvo]);
    GLD16(gA1,      &As[0][4096 + wvo]);
    GLD16(gB0,      &Bs[0][wvo]);
    GLD16(gB1,      &Bs[0][4096 + wvo]);
    GLD16(gA0 + 32, &As[1][wvo]);
    GLD16(gA1 + 32, &As[1][4096 + wvo]);
    GLD16(gB0 + 32, &Bs[1][wvo]);
    GLD16(gB1 + 32, &Bs[1][4096 + wvo]);
    asm volatile("s_waitcnt vmcnt(4)" ::: "memory");
    __builtin_amdgcn_s_barrier();
    MEMFENCE();

    unsigned short *cA = &As[0][0], *n1A = &As[1][0], *n2A = &As[2][0];
    unsigned short *cB = &Bs[0][0], *n1B = &Bs[1][0], *n2B = &Bs[2][0];

    #pragma unroll 1
    for (int kt = 0; kt < NT2; ++kt) {
        const bool pf = kt < NT2 - 2;
        const int koff = kt * BK2 + 64;           // k offset of tile kt+2

        // ---- phase A: ds-read a[0..3] + b[0..3]; stage A halves of tile kt+2
        bf16x8 a0[4], b0[4];
        #pragma unroll
        for (int mi = 0; mi < 4; ++mi)
            a0[mi] = *reinterpret_cast<const bf16x8*>(cA + aoff + mi * 16 * BK2);
        #pragma unroll
        for (int ni = 0; ni < 4; ++ni)
            b0[ni] = *reinterpret_cast<const bf16x8*>(cB + boff + ni * 16 * BK2);
        if (pf) {
            GLD16(gA0 + koff, n2A + wvo);
            GLD16(gA1 + koff, n2A + 4096 + wvo);
        }
        MEMFENCE();
        __builtin_amdgcn_s_barrier();
        MEMFENCE();
        __builtin_amdgcn_s_setprio(1);
        #pragma unroll
        for (int mi = 0; mi < 4; ++mi)
            #pragma unroll
            for (int ni = 0; ni < 4; ++ni)
                acc[mi][ni] = __builtin_amdgcn_mfma_f32_16x16x32_bf16(
                    a0[mi], b0[ni], acc[mi][ni], 0, 0, 0);
        __builtin_amdgcn_s_setprio(0);
        MEMFENCE();
        __builtin_amdgcn_s_barrier();
        MEMFENCE();

        // ---- phase B: ds-read a[4..7] (b0 reused); stage B halves of tile kt+2
        bf16x8 a1[4];
        #pragma unroll
        for (int mi = 0; mi < 4; ++mi)
            a1[mi] = *reinterpret_cast<const bf16x8*>(cA + aoff + (mi + 4) * 16 * BK2);
        if (pf) {
            GLD16(gB0 + koff, n2B + wvo);
            GLD16(gB1 + koff, n2B + 4096 + wvo);
        }
        MEMFENCE();
        __builtin_amdgcn_s_barrier();
        MEMFENCE();
        __builtin_amdgcn_s_setprio(1);
        #pragma unroll
        for (int mi = 0; mi < 4; ++mi)
            #pragma unroll
            for (int ni = 0; ni < 4; ++ni)
                acc[mi + 4][ni] = __builtin_amdgcn_mfma_f32_16x16x32_bf16(
                    a1[mi], b0[ni], acc[mi + 4][ni], 0, 0, 0);
        __builtin_amdgcn_s_setprio(0);
        // counted tile-boundary wait: tile kt+1's 4 loads retired,
        // tile kt+2's 4 stay in flight (never vmcnt(0) in steady state)
        if (kt < NT2 - 2)       asm volatile("s_waitcnt vmcnt(4)" ::: "memory");
        else if (kt == NT2 - 2) asm volatile("s_waitcnt vmcnt(0)" ::: "memory");
        __builtin_amdgcn_s_barrier();
        MEMFENCE();

        // rotate triple buffers
        unsigned short* t;
        t = cA; cA = n1A; n1A = n2A; n2A = t;
        t = cB; cB = n1B; n1B = n2B; n2B = t;
    }

    // epilogue: D[m = quad*4 + r][n = l16] per fragment, fused bias
    #pragma unroll
    for (int ni = 0; ni < 4; ++ni) {
        const int n = bn0 + wni * 64 + ni * 16 + l16;
        const float bv = bias[n];
        #pragma unroll
        for (int mi = 0; mi < 8; ++mi) {
            #pragma unroll
            for (int r = 0; r < 4; ++r) {
                const int m = bm0 + wmi * 128 + mi * 16 + quad * 4 + r;
                out[(size_t)m * N_DIM + n] = acc[mi][ni][r] + bv;
            }
        }
    }
}

// ---------------------------------------------------------------------------
// Fallback (round-2 passing kernel): fused dequant GEMM, used if ws too small.
__global__ __launch_bounds__(256, 2)
void l4b_mfma(const float* __restrict__ x, const int* __restrict__ qw,
              const float* __restrict__ scales, const int* __restrict__ qz,
              const float* __restrict__ bias, float* __restrict__ out)
{
    __shared__ unsigned short As[BM][BK];
    __shared__ unsigned short Bs[BK][BN];

    const int tid = threadIdx.x;
    const int bn0 = blockIdx.x * BN;
    const int bm0 = blockIdx.y * BM;
    const int ar = tid >> 3;
    const int ac = (tid & 7) << 2;
    const int bng = tid & 15;
    const int bkr = tid >> 4;
    const int nq  = (bn0 >> 3) + bng;

    float s8[8], zs8[8];
    {
        const unsigned zq = (unsigned)qz[nq];
        const float4 slo = *reinterpret_cast<const float4*>(scales + bn0 + bng * 8);
        const float4 shi = *reinterpret_cast<const float4*>(scales + bn0 + bng * 8 + 4);
        s8[0] = slo.x; s8[1] = slo.y; s8[2] = slo.z; s8[3] = slo.w;
        s8[4] = shi.x; s8[5] = shi.y; s8[6] = shi.z; s8[7] = shi.w;
        #pragma unroll
        for (int j = 0; j < 8; ++j)
            zs8[j] = (float)((zq >> (4 * j)) & 0xFu) * s8[j];
    }

    const int lane = tid & 63;
    const int wv   = tid >> 6;
    const int quad = lane >> 4;
    const int l16  = lane & 15;
    const int wm   = (wv >> 1) * 64;
    const int wn   = (wv & 1) * 64;

    f32x4 acc[4][4] = {};

    for (int k0 = 0; k0 < K_DIM; k0 += BK) {
        __syncthreads();
        #pragma unroll
        for (int p = 0; p < 4; ++p) {
            const int row = ar + p * 32;
            const float4 v = *reinterpret_cast<const float4*>(
                x + (size_t)(bm0 + row) * K_DIM + (k0 + ac));
            *reinterpret_cast<unsigned*>(&As[row][ac])     = pack2bf(v.x, v.y);
            *reinterpret_cast<unsigned*>(&As[row][ac + 2]) = pack2bf(v.z, v.w);
        }
        #pragma unroll
        for (int p = 0; p < 2; ++p) {
            const int kk = bkr + p * 16;
            const unsigned q  = (unsigned)qw[(size_t)(k0 + kk) * NPACK + nq];
            const unsigned qe = q & 0x0F0F0F0Fu;
            const unsigned qo = (q >> 4) & 0x0F0F0F0Fu;
            float f[8];
            f[0] = (float)(qe & 0xFFu);
            f[1] = (float)(qo & 0xFFu);
            f[2] = (float)((qe >> 8) & 0xFFu);
            f[3] = (float)((qo >> 8) & 0xFFu);
            f[4] = (float)((qe >> 16) & 0xFFu);
            f[5] = (float)((qo >> 16) & 0xFFu);
            f[6] = (float)((qe >> 24) & 0xFFu);
            f[7] = (float)((qo >> 24) & 0xFFu);
            #pragma unroll
            for (int j = 0; j < 4; ++j) {
                const float w0 = fmaf(f[2 * j],     s8[2 * j],     -zs8[2 * j]);
                const float w1 = fmaf(f[2 * j + 1], s8[2 * j + 1], -zs8[2 * j + 1]);
                *reinterpret_cast<unsigned*>(&Bs[kk][bng * 8 + 2 * j]) = pack2bf(w0, w1);
            }
        }
        __syncthreads();

        bf16x8 af[4], bfr[4];
        #pragma unroll
        for (int mi = 0; mi < 4; ++mi)
            af[mi] = *reinterpret_cast<const bf16x8*>(&As[wm + mi * 16 + l16][quad * 8]);
        #pragma unroll
        for (int ni = 0; ni < 4; ++ni) {
            u16x8 bu;
            #pragma unroll
            for (int jj = 0; jj < 8; ++jj)
                bu[jj] = Bs[quad * 8 + jj][wn + ni * 16 + l16];
            bfr[ni] = __builtin_bit_cast(bf16x8, bu);
        }
        #pragma unroll
        for (int mi = 0; mi < 4; ++mi) {
            #pragma unroll
            for (int ni = 0; ni < 4; ++ni)
                acc[mi][ni] = __builtin_amdgcn_mfma_f32_16x16x32_bf16(
                    af[mi], bfr[ni], acc[mi][ni], 0, 0, 0);
        }
    }

    #pragma unroll
    for (int ni = 0; ni < 4; ++ni) {
        const int n = bn0 + wn + ni * 16 + l16;
        const float bv = bias[n];
        #pragma unroll
        for (int mi = 0; mi < 4; ++mi) {
            #pragma unroll
            for (int r = 0; r < 4; ++r) {
                const int m = bm0 + wm + mi * 16 + quad * 4 + r;
                out[(size_t)m * N_DIM + n] = acc[mi][ni][r] + bv;
            }
        }
    }
}

extern "C" void kernel_launch(void* const* d_in, const int* in_sizes, int n_in,
                              void* d_out, int out_size, void* d_ws, size_t ws_size,
                              hipStream_t stream)
{
    (void)n_in; (void)out_size;
    const float* x      = (const float*)d_in[0];
    const int*   qw     = (const int*)d_in[1];
    const float* scales = (const float*)d_in[2];
    const int*   qz     = (const int*)d_in[3];
    const float* bias   = (const float*)d_in[4];
    float* out = (float*)d_out;

    const int M = in_sizes[0] / K_DIM;                    // 8192
    const size_t xb_bytes = (size_t)M * K_DIM * 2;        // 64 MB
    const size_t wt_bytes = (size_t)N_DIM * K_DIM * 2;    // 90 MB

    if (ws_size >= xb_bytes + wt_bytes && (M % BM2) == 0) {
        unsigned short* xb = (unsigned short*)d_ws;
        unsigned short* wt = (unsigned short*)((char*)d_ws + xb_bytes);
        convert_x<<<(int)(((size_t)M * K_DIM) / (256 * 8)), 256, 0, stream>>>(x, xb);
        dequant_w<<<dim3(N_DIM / 64, K_DIM / 64), 256, 0, stream>>>(qw, scales, qz, wt);
        gemm256<<<dim3(N_DIM / BN2, M / BM2), 512, 0, stream>>>(xb, wt, bias, out);
    } else {
        dim3 grid(N_DIM / BN, M / BM);
        l4b_mfma<<<grid, dim3(256, 1, 1), 0, stream>>>(x, qw, scales, qz, bias, out);
    }
}

// Round 2
// 1224.080 us; speedup vs baseline: 1.0346x; 1.0346x over previous
//
#include <hip/hip_runtime.h>

#define K_DIM 4096
#define N_DIM 11008
#define NPACK (N_DIM / 8)   // 1376 packed int32 per k-row

// fallback (128^2) geometry
#define BM 128
#define BN 128
#define BK 32

// main gemm (256^2) geometry
#define BM2 256
#define BN2 256
#define BK2 32
#define NT2 (K_DIM / BK2)   // 128 K-tiles

typedef __bf16 bf16x8 __attribute__((ext_vector_type(8)));
typedef float f32x4 __attribute__((ext_vector_type(4)));
typedef unsigned short u16x8 __attribute__((ext_vector_type(8)));

// fp32 -> bf16 bits, round-to-nearest-even (finite inputs only)
__device__ __forceinline__ unsigned short f2bf(float f) {
    unsigned u = __builtin_bit_cast(unsigned, f);
    return (unsigned short)((u + 0x7FFFu + ((u >> 16) & 1u)) >> 16);
}
__device__ __forceinline__ unsigned pack2bf(float a, float b) {
    return (unsigned)f2bf(a) | ((unsigned)f2bf(b) << 16);
}

// async global->LDS, 16B per lane; LDS dest = wave-uniform base + lane*16
#define GLD16(gp, lp) __builtin_amdgcn_global_load_lds(                       \
    (const __attribute__((address_space(1))) void*)(gp),                      \
    (__attribute__((address_space(3))) void*)(lp), 16, 0, 0)

#define MEMFENCE() asm volatile("" ::: "memory")

// ---------------------------------------------------------------------------
// Prepass 1: x fp32 [M][K] -> bf16 [M][K]. 8 elements/thread.
__global__ __launch_bounds__(256)
void convert_x(const float* __restrict__ x, unsigned short* __restrict__ xb)
{
    const size_t i = ((size_t)blockIdx.x * 256 + threadIdx.x) * 8;
    const float4 v0 = *reinterpret_cast<const float4*>(x + i);
    const float4 v1 = *reinterpret_cast<const float4*>(x + i + 4);
    u16x8 o;
    o[0] = f2bf(v0.x); o[1] = f2bf(v0.y); o[2] = f2bf(v0.z); o[3] = f2bf(v0.w);
    o[4] = f2bf(v1.x); o[5] = f2bf(v1.y); o[6] = f2bf(v1.z); o[7] = f2bf(v1.w);
    *reinterpret_cast<u16x8*>(xb + i) = o;
}

// ---------------------------------------------------------------------------
// Prepass 2: dequant int4 W[k][n] -> bf16 Wt[n][k] (transposed), 64x64 tiles.
__global__ __launch_bounds__(256)
void dequant_w(const int* __restrict__ qw, const float* __restrict__ scales,
               const int* __restrict__ qz, unsigned short* __restrict__ wt)
{
    __shared__ unsigned short T[64][76];   // [k][n], +12 pad halves col-read conflicts
    const int n0 = blockIdx.x * 64;
    const int k0 = blockIdx.y * 64;
    const int tid = threadIdx.x;

    #pragma unroll
    for (int h = 0; h < 2; ++h) {
        const int ii = tid + h * 256;            // [0,512): 64 k-rows x 8 packed ints
        const int kl = ii >> 3;
        const int nq = ii & 7;
        const unsigned q  = (unsigned)qw[(size_t)(k0 + kl) * NPACK + (n0 >> 3) + nq];
        const unsigned zq = (unsigned)qz[(n0 >> 3) + nq];
        const float4 s0 = *reinterpret_cast<const float4*>(scales + n0 + nq * 8);
        const float4 s1 = *reinterpret_cast<const float4*>(scales + n0 + nq * 8 + 4);
        const float s[8] = {s0.x, s0.y, s0.z, s0.w, s1.x, s1.y, s1.z, s1.w};
        u16x8 o;
        #pragma unroll
        for (int j = 0; j < 8; ++j) {
            const int   nib = (int)((q  >> (4 * j)) & 0xFu);
            const int   zp  = (int)((zq >> (4 * j)) & 0xFu);
            o[j] = f2bf((float)(nib - zp) * s[j]);
        }
        *reinterpret_cast<u16x8*>(&T[kl][nq * 8]) = o;
    }
    __syncthreads();
    #pragma unroll
    for (int h = 0; h < 2; ++h) {
        const int oo = tid + h * 256;            // [0,512): 64 n-rows x 8 k-chunks
        const int nl = oo >> 3;
        const int c  = oo & 7;
        u16x8 o;
        #pragma unroll
        for (int r = 0; r < 8; ++r) o[r] = T[c * 8 + r][nl];
        *reinterpret_cast<u16x8*>(wt + (size_t)(n0 + nl) * K_DIM + k0 + c * 8) = o;
    }
}

// ---------------------------------------------------------------------------
// Main GEMM: A bf16 [M][K], B bf16 [N][K] (both k-contiguous), out fp32 [M][N].
// 256x256 tile, 512 threads / 8 waves (2M x 4N), BK=32, triple-buffered LDS,
// depth-2 prefetch with counted vmcnt(4) across tile barriers (T3+T4),
// setprio around MFMA clusters (T5), XCD-chunked raster (T1).
//
// LDS swizzle (rule 21, both-sides-or-neither): a 64 B row stride puts each
// quad-group's 16 lanes on 2 four-bank slots (8-way conflict, measured
// 6.76e7 conflict cycles). Fix: physical 16B chunk c = q ^ ((row>>1)&3).
// global_load_lds dest stays LINEAR; the SOURCE chunk is pre-permuted and
// the ds_read applies the same XOR -> 8 distinct slots, 2 lanes each (free).
__global__ __launch_bounds__(512, 2)
void gemm256(const unsigned short* __restrict__ A, const unsigned short* __restrict__ B,
             const float* __restrict__ bias, float* __restrict__ out)
{
    __shared__ unsigned short As[3][BM2 * BK2];   // 3 x 16 KB
    __shared__ unsigned short Bs[3][BN2 * BK2];   // 3 x 16 KB  (96 KB total)

    const int tid  = threadIdx.x;
    const int lane = tid & 63;
    const int wv   = tid >> 6;

    // block raster: 1376 = 8 XCD chunks of 172 = (4 M-rows x 43 N-cols),
    // column-major within chunk -> B panel L2-hit x4, A set cycles per XCD.
    int bx, by;
    if (gridDim.x == 43 && gridDim.y == 32) {
        const int bid = (int)(blockIdx.y * 43 + blockIdx.x);
        const int g   = bid & 7;          // XCD
        const int loc = bid >> 3;         // [0,172)
        by = g * 4 + (loc & 3);
        bx = loc >> 2;
    } else {
        bx = blockIdx.x; by = blockIdx.y;
    }
    const int bm0 = by * BM2;
    const int bn0 = bx * BN2;

    // staging geometry: thread t covers row (t>>2) of a 128-row half.
    // physical chunk = t&3 (linear LDS dest); logical source chunk is
    // pre-swizzled: q = (t&3) ^ ((srow>>1)&3).
    const int srow = tid >> 2;
    const int sc   = ((tid & 3) ^ ((srow >> 1) & 3)) * 8;
    const unsigned short* gA0 = A + (size_t)(bm0 + srow) * K_DIM + sc;
    const unsigned short* gA1 = gA0 + (size_t)128 * K_DIM;
    const unsigned short* gB0 = B + (size_t)(bn0 + srow) * K_DIM + sc;
    const unsigned short* gB1 = gB0 + (size_t)128 * K_DIM;
    const int wvo = wv * 512;             // wave chunk offset within a 128-row half (ushorts)

    // fragment geometry (verified 16x16x32 layout from prior kernel)
    const int quad = lane >> 4;
    const int l16  = lane & 15;
    const int wmi  = wv >> 2;             // M half   (128 rows)
    const int wni  = wv & 3;              // N quarter (64 cols)
    // read-side swizzle: row bits 1..2 == l16 bits 1..2 (frag bases are x16)
    const int fsw  = (l16 >> 1) & 3;
    const int aoff = (wmi * 128 + l16) * BK2 + ((quad ^ fsw) * 8);
    const int boff = (wni * 64  + l16) * BK2 + ((quad ^ fsw) * 8);

    f32x4 acc[8][4] = {};

    // prologue: stage tiles 0 and 1; keep tile1's 4 loads in flight
    GLD16(gA0,      &As[0][wvo]);
    GLD16(gA1,      &As[0][4096 + wvo]);
    GLD16(gB0,      &Bs[0][wvo]);
    GLD16(gB1,      &Bs[0][4096 + wvo]);
    GLD16(gA0 + 32, &As[1][wvo]);
    GLD16(gA1 + 32, &As[1][4096 + wvo]);
    GLD16(gB0 + 32, &Bs[1][wvo]);
    GLD16(gB1 + 32, &Bs[1][4096 + wvo]);
    asm volatile("s_waitcnt vmcnt(4)" ::: "memory");
    __builtin_amdgcn_s_barrier();
    MEMFENCE();

    unsigned short *cA = &As[0][0], *n1A = &As[1][0], *n2A = &As[2][0];
    unsigned short *cB = &Bs[0][0], *n1B = &Bs[1][0], *n2B = &Bs[2][0];

    #pragma unroll 1
    for (int kt = 0; kt < NT2; ++kt) {
        const bool pf = kt < NT2 - 2;
        const int koff = kt * BK2 + 64;           // k offset of tile kt+2

        // ---- phase A: ds-read a[0..3] + b[0..3]; stage A halves of tile kt+2
        bf16x8 a0[4], b0[4];
        #pragma unroll
        for (int mi = 0; mi < 4; ++mi)
            a0[mi] = *reinterpret_cast<const bf16x8*>(cA + aoff + mi * 16 * BK2);
        #pragma unroll
        for (int ni = 0; ni < 4; ++ni)
            b0[ni] = *reinterpret_cast<const bf16x8*>(cB + boff + ni * 16 * BK2);
        if (pf) {
            GLD16(gA0 + koff, n2A + wvo);
            GLD16(gA1 + koff, n2A + 4096 + wvo);
        }
        MEMFENCE();
        __builtin_amdgcn_s_barrier();
        MEMFENCE();
        __builtin_amdgcn_s_setprio(1);
        #pragma unroll
        for (int mi = 0; mi < 4; ++mi)
            #pragma unroll
            for (int ni = 0; ni < 4; ++ni)
                acc[mi][ni] = __builtin_amdgcn_mfma_f32_16x16x32_bf16(
                    a0[mi], b0[ni], acc[mi][ni], 0, 0, 0);
        __builtin_amdgcn_s_setprio(0);
        MEMFENCE();
        __builtin_amdgcn_s_barrier();
        MEMFENCE();

        // ---- phase B: ds-read a[4..7] (b0 reused); stage B halves of tile kt+2
        bf16x8 a1[4];
        #pragma unroll
        for (int mi = 0; mi < 4; ++mi)
            a1[mi] = *reinterpret_cast<const bf16x8*>(cA + aoff + (mi + 4) * 16 * BK2);
        if (pf) {
            GLD16(gB0 + koff, n2B + wvo);
            GLD16(gB1 + koff, n2B + 4096 + wvo);
        }
        MEMFENCE();
        __builtin_amdgcn_s_barrier();
        MEMFENCE();
        __builtin_amdgcn_s_setprio(1);
        #pragma unroll
        for (int mi = 0; mi < 4; ++mi)
            #pragma unroll
            for (int ni = 0; ni < 4; ++ni)
                acc[mi + 4][ni] = __builtin_amdgcn_mfma_f32_16x16x32_bf16(
                    a1[mi], b0[ni], acc[mi + 4][ni], 0, 0, 0);
        __builtin_amdgcn_s_setprio(0);
        // counted tile-boundary wait: tile kt+1's 4 loads retired,
        // tile kt+2's 4 stay in flight (never vmcnt(0) in steady state)
        if (kt < NT2 - 2)       asm volatile("s_waitcnt vmcnt(4)" ::: "memory");
        else if (kt == NT2 - 2) asm volatile("s_waitcnt vmcnt(0)" ::: "memory");
        __builtin_amdgcn_s_barrier();
        MEMFENCE();

        // rotate triple buffers
        unsigned short* t;
        t = cA; cA = n1A; n1A = n2A; n2A = t;
        t = cB; cB = n1B; n1B = n2B; n2B = t;
    }

    // epilogue: D[m = quad*4 + r][n = l16] per fragment, fused bias
    #pragma unroll
    for (int ni = 0; ni < 4; ++ni) {
        const int n = bn0 + wni * 64 + ni * 16 + l16;
        const float bv = bias[n];
        #pragma unroll
        for (int mi = 0; mi < 8; ++mi) {
            #pragma unroll
            for (int r = 0; r < 4; ++r) {
                const int m = bm0 + wmi * 128 + mi * 16 + quad * 4 + r;
                out[(size_t)m * N_DIM + n] = acc[mi][ni][r] + bv;
            }
        }
    }
}

// ---------------------------------------------------------------------------
// Fallback (round-2 passing kernel): fused dequant GEMM, used if ws too small.
__global__ __launch_bounds__(256, 2)
void l4b_mfma(const float* __restrict__ x, const int* __restrict__ qw,
              const float* __restrict__ scales, const int* __restrict__ qz,
              const float* __restrict__ bias, float* __restrict__ out)
{
    __shared__ unsigned short As[BM][BK];
    __shared__ unsigned short Bs[BK][BN];

    const int tid = threadIdx.x;
    const int bn0 = blockIdx.x * BN;
    const int bm0 = blockIdx.y * BM;
    const int ar = tid >> 3;
    const int ac = (tid & 7) << 2;
    const int bng = tid & 15;
    const int bkr = tid >> 4;
    const int nq  = (bn0 >> 3) + bng;

    float s8[8], zs8[8];
    {
        const unsigned zq = (unsigned)qz[nq];
        const float4 slo = *reinterpret_cast<const float4*>(scales + bn0 + bng * 8);
        const float4 shi = *reinterpret_cast<const float4*>(scales + bn0 + bng * 8 + 4);
        s8[0] = slo.x; s8[1] = slo.y; s8[2] = slo.z; s8[3] = slo.w;
        s8[4] = shi.x; s8[5] = shi.y; s8[6] = shi.z; s8[7] = shi.w;
        #pragma unroll
        for (int j = 0; j < 8; ++j)
            zs8[j] = (float)((zq >> (4 * j)) & 0xFu) * s8[j];
    }

    const int lane = tid & 63;
    const int wv   = tid >> 6;
    const int quad = lane >> 4;
    const int l16  = lane & 15;
    const int wm   = (wv >> 1) * 64;
    const int wn   = (wv & 1) * 64;

    f32x4 acc[4][4] = {};

    for (int k0 = 0; k0 < K_DIM; k0 += BK) {
        __syncthreads();
        #pragma unroll
        for (int p = 0; p < 4; ++p) {
            const int row = ar + p * 32;
            const float4 v = *reinterpret_cast<const float4*>(
                x + (size_t)(bm0 + row) * K_DIM + (k0 + ac));
            *reinterpret_cast<unsigned*>(&As[row][ac])     = pack2bf(v.x, v.y);
            *reinterpret_cast<unsigned*>(&As[row][ac + 2]) = pack2bf(v.z, v.w);
        }
        #pragma unroll
        for (int p = 0; p < 2; ++p) {
            const int kk = bkr + p * 16;
            const unsigned q  = (unsigned)qw[(size_t)(k0 + kk) * NPACK + nq];
            const unsigned qe = q & 0x0F0F0F0Fu;
            const unsigned qo = (q >> 4) & 0x0F0F0F0Fu;
            float f[8];
            f[0] = (float)(qe & 0xFFu);
            f[1] = (float)(qo & 0xFFu);
            f[2] = (float)((qe >> 8) & 0xFFu);
            f[3] = (float)((qo >> 8) & 0xFFu);
            f[4] = (float)((qe >> 16) & 0xFFu);
            f[5] = (float)((qo >> 16) & 0xFFu);
            f[6] = (float)((qe >> 24) & 0xFFu);
            f[7] = (float)((qo >> 24) & 0xFFu);
            #pragma unroll
            for (int j = 0; j < 4; ++j) {
                const float w0 = fmaf(f[2 * j],     s8[2 * j],     -zs8[2 * j]);
                const float w1 = fmaf(f[2 * j + 1], s8[2 * j + 1], -zs8[2 * j + 1]);
                *reinterpret_cast<unsigned*>(&Bs[kk][bng * 8 + 2 * j]) = pack2bf(w0, w1);
            }
        }
        __syncthreads();

        bf16x8 af[4], bfr[4];
        #pragma unroll
        for (int mi = 0; mi < 4; ++mi)
            af[mi] = *reinterpret_cast<const bf16x8*>(&As[wm + mi * 16 + l16][quad * 8]);
        #pragma unroll
        for (int ni = 0; ni < 4; ++ni) {
            u16x8 bu;
            #pragma unroll
            for (int jj = 0; jj < 8; ++jj)
                bu[jj] = Bs[quad * 8 + jj][wn + ni * 16 + l16];
            bfr[ni] = __builtin_bit_cast(bf16x8, bu);
        }
        #pragma unroll
        for (int mi = 0; mi < 4; ++mi) {
            #pragma unroll
            for (int ni = 0; ni < 4; ++ni)
                acc[mi][ni] = __builtin_amdgcn_mfma_f32_16x16x32_bf16(
                    af[mi], bfr[ni], acc[mi][ni], 0, 0, 0);
        }
    }

    #pragma unroll
    for (int ni = 0; ni < 4; ++ni) {
        const int n = bn0 + wn + ni * 16 + l16;
        const float bv = bias[n];
        #pragma unroll
        for (int mi = 0; mi < 4; ++mi) {
            #pragma unroll
            for (int r = 0; r < 4; ++r) {
                const int m = bm0 + wm + mi * 16 + quad * 4 + r;
                out[(size_t)m * N_DIM + n] = acc[mi][ni][r] + bv;
            }
        }
    }
}

extern "C" void kernel_launch(void* const* d_in, const int* in_sizes, int n_in,
                              void* d_out, int out_size, void* d_ws, size_t ws_size,
                              hipStream_t stream)
{
    (void)n_in; (void)out_size;
    const float* x      = (const float*)d_in[0];
    const int*   qw     = (const int*)d_in[1];
    const float* scales = (const float*)d_in[2];
    const int*   qz     = (const int*)d_in[3];
    const float* bias   = (const float*)d_in[4];
    float* out = (float*)d_out;

    const int M = in_sizes[0] / K_DIM;                    // 8192
    const size_t xb_bytes = (size_t)M * K_DIM * 2;        // 64 MB
    const size_t wt_bytes = (size_t)N_DIM * K_DIM * 2;    // 90 MB

    if (ws_size >= xb_bytes + wt_bytes && (M % BM2) == 0) {
        unsigned short* xb = (unsigned short*)d_ws;
        unsigned short* wt = (unsigned short*)((char*)d_ws + xb_bytes);
        convert_x<<<(int)(((size_t)M * K_DIM) / (256 * 8)), 256, 0, stream>>>(x, xb);
        dequant_w<<<dim3(N_DIM / 64, K_DIM / 64), 256, 0, stream>>>(qw, scales, qz, wt);
        gemm256<<<dim3(N_DIM / BN2, M / BM2), 512, 0, stream>>>(xb, wt, bias, out);
    } else {
        dim3 grid(N_DIM / BN, M / BM);
        l4b_mfma<<<grid, dim3(256, 1, 1), 0, stream>>>(x, qw, scales, qz, bias, out);
    }
}